// Round 1
// baseline (1738.481 us; speedup 1.0000x reference)
//
#include <hip/hip_runtime.h>
#include <math.h>

#define B_ 8
#define S_ 1024
#define D_ 768
#define H_ 12
// DH = 64

__device__ __forceinline__ float4 f4fma(float4 a, float s, float4 w) {
  a.x += s * w.x; a.y += s * w.y; a.z += s * w.z; a.w += s * w.w;
  return a;
}

// ---------------- LayerNorm (one block per row of 768) ----------------
__global__ __launch_bounds__(256) void ln_kernel(
    const float* __restrict__ in, const float* __restrict__ g,
    const float* __restrict__ bias, float* __restrict__ out) {
  const int row = blockIdx.x;
  const int tid = threadIdx.x;
  const float* p = in + (size_t)row * D_;
  const float v0 = p[tid], v1 = p[tid + 256], v2 = p[tid + 512];
  __shared__ float red[256];
  red[tid] = v0 + v1 + v2;
  __syncthreads();
  for (int off = 128; off > 0; off >>= 1) {
    if (tid < off) red[tid] += red[tid + off];
    __syncthreads();
  }
  const float mean = red[0] * (1.0f / D_);
  __syncthreads();
  const float d0 = v0 - mean, d1 = v1 - mean, d2 = v2 - mean;
  red[tid] = d0 * d0 + d1 * d1 + d2 * d2;
  __syncthreads();
  for (int off = 128; off > 0; off >>= 1) {
    if (tid < off) red[tid] += red[tid + off];
    __syncthreads();
  }
  const float rstd = rsqrtf(red[0] * (1.0f / D_) + 1e-5f);
  float* q = out + (size_t)row * D_;
  q[tid]       = d0 * rstd * g[tid]       + bias[tid];
  q[tid + 256] = d1 * rstd * g[tid + 256] + bias[tid + 256];
  q[tid + 512] = d2 * rstd * g[tid + 512] + bias[tid + 512];
}

// ---------------- per-head QKV projection ----------------
// block = 256 threads, handles (b, h, 64 s-rows). W tiles in LDS (48 KB),
// X head-slice staged transposed in LDS (16 KB) -> exactly 64 KB.
__global__ __launch_bounds__(256) void qkv_kernel(
    const float* __restrict__ xln,
    const float* __restrict__ Wq, const float* __restrict__ bq,
    const float* __restrict__ Wk, const float* __restrict__ bk,
    const float* __restrict__ Wv, const float* __restrict__ bv,
    float* __restrict__ qo, float* __restrict__ ko, float* __restrict__ vo) {
  const int bh = blockIdx.y;
  const int b = bh / H_, h = bh % H_;
  const int s0 = blockIdx.x * 64;
  const int tid = threadIdx.x;
  const int r = tid >> 2, eq = tid & 3, e0 = eq * 16;

  __shared__ float Wqs[64][64], Wks[64][64], Wvs[64][64];
  __shared__ float Xs[64][64];  // transposed: Xs[d][r]

  const float* wq = Wq + h * 4096;
  const float* wk = Wk + h * 4096;
  const float* wv = Wv + h * 4096;
#pragma unroll
  for (int i = 0; i < 16; ++i) {
    const int idx = tid + i * 256;
    (&Wqs[0][0])[idx] = wq[idx];
    (&Wks[0][0])[idx] = wk[idx];
    (&Wvs[0][0])[idx] = wv[idx];
    const int rr = idx >> 6, dd = idx & 63;
    Xs[dd][rr] = xln[(size_t)(b * S_ + s0 + rr) * D_ + h * 64 + dd];
  }
  __syncthreads();

  float4 aq[4] = {}, ak[4] = {}, av[4] = {};
#pragma unroll 8
  for (int d = 0; d < 64; ++d) {
    const float xv = Xs[d][r];  // broadcast across eq, 16 banks across r
    const float4* wq4 = (const float4*)(&Wqs[d][e0]);
    const float4* wk4 = (const float4*)(&Wks[d][e0]);
    const float4* wv4 = (const float4*)(&Wvs[d][e0]);
#pragma unroll
    for (int j = 0; j < 4; ++j) {
      aq[j] = f4fma(aq[j], xv, wq4[j]);
      ak[j] = f4fma(ak[j], xv, wk4[j]);
      av[j] = f4fma(av[j], xv, wv4[j]);
    }
  }
  const size_t obase = ((size_t)bh * S_ + (s0 + r)) * 64 + e0;
#pragma unroll
  for (int j = 0; j < 4; ++j) {
    const float4 bq4 = *(const float4*)(bq + h * 64 + e0 + j * 4);
    const float4 bk4 = *(const float4*)(bk + h * 64 + e0 + j * 4);
    const float4 bv4 = *(const float4*)(bv + h * 64 + e0 + j * 4);
    float4 t;
    t = aq[j]; t.x += bq4.x; t.y += bq4.y; t.z += bq4.z; t.w += bq4.w;
    *(float4*)(qo + obase + j * 4) = t;
    t = ak[j]; t.x += bk4.x; t.y += bk4.y; t.z += bk4.z; t.w += bk4.w;
    *(float4*)(ko + obase + j * 4) = t;
    t = av[j]; t.x += bv4.x; t.y += bv4.y; t.z += bv4.z; t.w += bv4.w;
    *(float4*)(vo + obase + j * 4) = t;
  }
}

// ---------------- flash attention ----------------
// block = 256 threads = (tm 0..15 query-quads) x (tn 0..15 key/elem-quads).
// Handles (b, h, 64 queries). K tile and V tile share one LDS buffer
// (K dead after score phase); softmax (wave0) overlaps V load (waves 1-3).
__global__ __launch_bounds__(256) void attn_kernel(
    const float* __restrict__ q, const float* __restrict__ k,
    const float* __restrict__ v, float* __restrict__ o) {
  const int bh = blockIdx.y;
  const int b = bh / H_, h = bh % H_;
  const int q0 = blockIdx.x * 64;
  const int tid = threadIdx.x;
  const int tn = tid & 15, tm = tid >> 4;

  __shared__ float Qt[64][68];   // Qt[d][q]  (pre-scaled by 1/8)
  __shared__ float buf[64][68];  // Kt[d][t] in score phase; V[t][d] in accum
  __shared__ float Pt[64][68];   // Pt[t][q]  scores then probs
  __shared__ float m_s[64], l_s[64], a_s[64];

  const float* qp = q + ((size_t)bh * S_ + q0) * 64;
#pragma unroll
  for (int i = 0; i < 16; ++i) {
    const int idx = tid + i * 256;
    const int rr = idx >> 6, dd = idx & 63;
    Qt[dd][rr] = qp[idx] * 0.125f;  // 1/sqrt(64)
  }
  if (tid < 64) { m_s[tid] = -INFINITY; l_s[tid] = 0.0f; }
  float4 oa[4] = {};  // oa[i] = O[q=tm*4+i][e=tn*4..tn*4+3]
  __syncthreads();

  const float* kp = k + (size_t)bh * S_ * 64;
  const float* vp = v + (size_t)bh * S_ * 64;

  for (int kt = 0; kt < 16; ++kt) {
    const float* kp2 = kp + kt * 4096;
#pragma unroll
    for (int i = 0; i < 16; ++i) {
      const int idx = tid + i * 256;
      const int tt = idx >> 6, dd = idx & 63;
      buf[dd][tt] = kp2[idx];  // transpose into Kt[d][t]
    }
    __syncthreads();

    // scores: S[q][t] = sum_d Qt[d][q] * Kt[d][t]
    float4 sc[4] = {};
#pragma unroll 8
    for (int d = 0; d < 64; ++d) {
      const float4 kf = *(const float4*)(&buf[d][tn * 4]);
      const float4 qf = *(const float4*)(&Qt[d][tm * 4]);
      const float qv[4] = {qf.x, qf.y, qf.z, qf.w};
#pragma unroll
      for (int i = 0; i < 4; ++i) sc[i] = f4fma(sc[i], qv[i], kf);
    }
#pragma unroll
    for (int i = 0; i < 4; ++i) {  // write transposed Pt[t][q]
      Pt[tn * 4 + 0][tm * 4 + i] = sc[i].x;
      Pt[tn * 4 + 1][tm * 4 + i] = sc[i].y;
      Pt[tn * 4 + 2][tm * 4 + i] = sc[i].z;
      Pt[tn * 4 + 3][tm * 4 + i] = sc[i].w;
    }
    __syncthreads();

    if (tid < 64) {  // wave 0: online softmax along t for query column tid
      const int qq = tid;
      const float mold = m_s[qq];
      float tmax = -INFINITY;
#pragma unroll 8
      for (int t = 0; t < 64; ++t) tmax = fmaxf(tmax, Pt[t][qq]);
      const float mnew = fmaxf(mold, tmax);
      const float corr = __expf(mold - mnew);  // first tile: exp(-inf)=0
      float sum = 0.0f;
#pragma unroll 8
      for (int t = 0; t < 64; ++t) {
        const float pv = __expf(Pt[t][qq] - mnew);
        Pt[t][qq] = pv;
        sum += pv;
      }
      l_s[qq] = l_s[qq] * corr + sum;
      m_s[qq] = mnew;
      a_s[qq] = corr;
    } else {  // waves 1-3: load V tile into buf (K is dead now)
      const float* vp2 = vp + kt * 4096;
      for (int i2 = tid - 64; i2 < 4096; i2 += 192) {
        const int tt = i2 >> 6, dd = i2 & 63;
        buf[tt][dd] = vp2[i2];  // natural V[t][d]
      }
    }
    __syncthreads();

    // rescale + accumulate O += P * V
#pragma unroll
    for (int i = 0; i < 4; ++i) {
      const float c = a_s[tm * 4 + i];
      oa[i].x *= c; oa[i].y *= c; oa[i].z *= c; oa[i].w *= c;
    }
#pragma unroll 8
    for (int t = 0; t < 64; ++t) {
      const float4 p4 = *(const float4*)(&Pt[t][tm * 4]);
      const float4 v4 = *(const float4*)(&buf[t][tn * 4]);
      const float pv[4] = {p4.x, p4.y, p4.z, p4.w};
#pragma unroll
      for (int i = 0; i < 4; ++i) oa[i] = f4fma(oa[i], pv[i], v4);
    }
    __syncthreads();
  }

  float* op = o + ((size_t)(b * S_) + q0) * D_ + h * 64 + tn * 4;
#pragma unroll
  for (int i = 0; i < 4; ++i) {
    const float invl = 1.0f / l_s[tm * 4 + i];
    float4 t = oa[i];
    t.x *= invl; t.y *= invl; t.z *= invl; t.w *= invl;
    *(float4*)(op + (size_t)(tm * 4 + i) * D_) = t;
  }
}

// ---------------- elementwise residual add ----------------
__global__ __launch_bounds__(256) void add_kernel(
    const float4* __restrict__ a, const float4* __restrict__ b,
    float4* __restrict__ o, int n4) {
  int i = blockIdx.x * 256 + threadIdx.x;
  const int st = gridDim.x * 256;
  for (; i < n4; i += st) {
    const float4 x = a[i], y = b[i];
    o[i] = make_float4(x.x + y.x, x.y + y.y, x.z + y.z, x.w + y.w);
  }
}

// ---------------- fp32 GEMM, 128x128 tile, 8x8 microtile ----------------
// C[M=8192, N] = A[8192, K] @ Bm[K, N]; optional exact-GELU / +resid epilogue.
// Microtile split as rows {tm*4+i, 64+tm*4+i}, cols {tn*4+j, 64+tn*4+j}
// so LDS reads stay <=2-way bank aliased.
template <int N, int K, bool GELU, bool RESID>
__global__ __launch_bounds__(256) void gemm_kernel(
    const float* __restrict__ A, const float* __restrict__ Bm,
    const float* __restrict__ resid, float* __restrict__ C) {
  const int nb = blockIdx.x * 128;
  const int mb = blockIdx.y * 128;
  const int tid = threadIdx.x;
  const int tn = tid & 15, tm = tid >> 4;
  __shared__ float As[16][132];  // A^T tile: As[k][m]
  __shared__ float Bs[16][132];  // Bs[k][n]
  float4 acc[8][2] = {};         // [row 0..7][col-group 0..1]

  for (int kb = 0; kb < K; kb += 16) {
#pragma unroll
    for (int i = 0; i < 8; ++i) {
      const int idx = tid + i * 256;
      const int m = idx >> 4, kk = idx & 15;
      As[kk][m] = A[(size_t)(mb + m) * K + kb + kk];
    }
#pragma unroll
    for (int i = 0; i < 2; ++i) {
      const int idx = tid + i * 256;
      const int kk = idx >> 5, n4 = (idx & 31) * 4;
      *(float4*)(&Bs[kk][n4]) =
          *(const float4*)(Bm + (size_t)(kb + kk) * N + nb + n4);
    }
    __syncthreads();
#pragma unroll
    for (int kk = 0; kk < 16; ++kk) {
      const float4 a0 = *(const float4*)(&As[kk][tm * 4]);
      const float4 a1 = *(const float4*)(&As[kk][64 + tm * 4]);
      const float4 b0 = *(const float4*)(&Bs[kk][tn * 4]);
      const float4 b1 = *(const float4*)(&Bs[kk][64 + tn * 4]);
      const float avv[8] = {a0.x, a0.y, a0.z, a0.w, a1.x, a1.y, a1.z, a1.w};
#pragma unroll
      for (int ii = 0; ii < 8; ++ii) {
        acc[ii][0] = f4fma(acc[ii][0], avv[ii], b0);
        acc[ii][1] = f4fma(acc[ii][1], avv[ii], b1);
      }
    }
    __syncthreads();
  }

#pragma unroll
  for (int ih = 0; ih < 2; ++ih)
#pragma unroll
    for (int ii = 0; ii < 4; ++ii) {
      const int m = mb + ih * 64 + tm * 4 + ii;
#pragma unroll
      for (int jh = 0; jh < 2; ++jh) {
        const int n0 = nb + jh * 64 + tn * 4;
        float4 rv = acc[ih * 4 + ii][jh];
        if (GELU) {
          rv.x = 0.5f * rv.x * (1.0f + erff(rv.x * 0.70710678f));
          rv.y = 0.5f * rv.y * (1.0f + erff(rv.y * 0.70710678f));
          rv.z = 0.5f * rv.z * (1.0f + erff(rv.z * 0.70710678f));
          rv.w = 0.5f * rv.w * (1.0f + erff(rv.w * 0.70710678f));
        }
        if (RESID) {
          const float4 rs = *(const float4*)(resid + (size_t)m * N + n0);
          rv.x += rs.x; rv.y += rs.y; rv.z += rs.z; rv.w += rs.w;
        }
        *(float4*)(C + (size_t)m * N + n0) = rv;
      }
    }
}

extern "C" void kernel_launch(void* const* d_in, const int* in_sizes, int n_in,
                              void* d_out, int out_size, void* d_ws, size_t ws_size,
                              hipStream_t stream) {
  (void)in_sizes; (void)n_in; (void)out_size; (void)ws_size;
  const float* x     = (const float*)d_in[0];
  const float* ln1_g = (const float*)d_in[1];
  const float* ln1_b = (const float*)d_in[2];
  const float* Wq    = (const float*)d_in[3];
  const float* bq    = (const float*)d_in[4];
  const float* Wk    = (const float*)d_in[5];
  const float* bk    = (const float*)d_in[6];
  const float* Wv    = (const float*)d_in[7];
  const float* bv    = (const float*)d_in[8];
  const float* ln2_g = (const float*)d_in[9];
  const float* ln2_b = (const float*)d_in[10];
  const float* W1    = (const float*)d_in[11];
  const float* W2    = (const float*)d_in[12];
  float* out = (float*)d_out;
  float* ws  = (float*)d_ws;

  const size_t n = (size_t)B_ * S_ * D_;  // 6,291,456 floats
  float* xln   = ws;            // LN1 out; later reused for LN2 out
  float* qb    = ws + n;        // (B,H,S,64)
  float* kb    = ws + 2 * n;
  float* vb    = ws + 3 * n;
  float* attno = ws + 4 * n;    // (B,S,D) concat heads
  float* out1  = ws + 5 * n;    // x + attn
  float* act   = ws + 6 * n;    // 8192 x 3072 gelu activations
  // ws use: 6*n + 25.2M floats = ~252 MB

  ln_kernel<<<dim3(8192), dim3(256), 0, stream>>>(x, ln1_g, ln1_b, xln);
  qkv_kernel<<<dim3(16, 96), dim3(256), 0, stream>>>(xln, Wq, bq, Wk, bk, Wv, bv,
                                                     qb, kb, vb);
  attn_kernel<<<dim3(16, 96), dim3(256), 0, stream>>>(qb, kb, vb, attno);
  add_kernel<<<dim3(2048), dim3(256), 0, stream>>>(
      (const float4*)x, (const float4*)attno, (float4*)out1, (int)(n / 4));
  ln_kernel<<<dim3(8192), dim3(256), 0, stream>>>(out1, ln2_g, ln2_b, xln);
  gemm_kernel<3072, 768, true, false><<<dim3(24, 64), dim3(256), 0, stream>>>(
      xln, W1, nullptr, act);
  gemm_kernel<768, 3072, false, true><<<dim3(6, 64), dim3(256), 0, stream>>>(
      act, W2, out1, out);
}

// Round 2
// 896.729 us; speedup vs baseline: 1.9387x; 1.9387x over previous
//
#include <hip/hip_runtime.h>
#include <math.h>

#define B_ 8
#define S_ 1024
#define D_ 768
#define H_ 12
// DH = 64

typedef __attribute__((ext_vector_type(8))) short short8;
typedef __attribute__((ext_vector_type(4))) float floatx4;
typedef unsigned short ushort_t;

__device__ __forceinline__ float4 f4fma(float4 a, float s, float4 w) {
  a.x += s * w.x; a.y += s * w.y; a.z += s * w.z; a.w += s * w.w;
  return a;
}

__device__ __forceinline__ ushort_t f2bf(float f) {  // RNE fp32 -> bf16
  unsigned int u = __builtin_bit_cast(unsigned int, f);
  u += 0x7fffu + ((u >> 16) & 1u);
  return (ushort_t)(u >> 16);
}

// ---------------- LayerNorm (one block per row of 768) ----------------
template <bool OBF>
__global__ __launch_bounds__(256) void ln_kernel(
    const float* __restrict__ in, const float* __restrict__ g,
    const float* __restrict__ bias, void* __restrict__ outv) {
  const int row = blockIdx.x;
  const int tid = threadIdx.x;
  const float* p = in + (size_t)row * D_;
  const float v0 = p[tid], v1 = p[tid + 256], v2 = p[tid + 512];
  __shared__ float red[256];
  red[tid] = v0 + v1 + v2;
  __syncthreads();
  for (int off = 128; off > 0; off >>= 1) {
    if (tid < off) red[tid] += red[tid + off];
    __syncthreads();
  }
  const float mean = red[0] * (1.0f / D_);
  __syncthreads();
  const float d0 = v0 - mean, d1 = v1 - mean, d2 = v2 - mean;
  red[tid] = d0 * d0 + d1 * d1 + d2 * d2;
  __syncthreads();
  for (int off = 128; off > 0; off >>= 1) {
    if (tid < off) red[tid] += red[tid + off];
    __syncthreads();
  }
  const float rstd = rsqrtf(red[0] * (1.0f / D_) + 1e-5f);
  const float o0 = d0 * rstd * g[tid]       + bias[tid];
  const float o1 = d1 * rstd * g[tid + 256] + bias[tid + 256];
  const float o2 = d2 * rstd * g[tid + 512] + bias[tid + 512];
  if (OBF) {
    ushort_t* q = (ushort_t*)outv + (size_t)row * D_;
    q[tid] = f2bf(o0); q[tid + 256] = f2bf(o1); q[tid + 512] = f2bf(o2);
  } else {
    float* q = (float*)outv + (size_t)row * D_;
    q[tid] = o0; q[tid + 256] = o1; q[tid + 512] = o2;
  }
}

// ---------------- transpose + cast: W (K x N fp32) -> Wt (N x K bf16) -----
__global__ __launch_bounds__(256) void transpose_cast(
    const float* __restrict__ W, ushort_t* __restrict__ Wt, int Kdim, int Ndim) {
  __shared__ float tile[32][33];
  const int n0 = blockIdx.x * 32, k0 = blockIdx.y * 32;
  const int tx = threadIdx.x & 31, ty = threadIdx.x >> 5;  // ty 0..7
#pragma unroll
  for (int i = 0; i < 32; i += 8)
    tile[ty + i][tx] = W[(size_t)(k0 + ty + i) * Ndim + n0 + tx];
  __syncthreads();
#pragma unroll
  for (int i = 0; i < 32; i += 8)
    Wt[(size_t)(n0 + ty + i) * Kdim + k0 + tx] = f2bf(tile[tx][ty + i]);
}

// ---------------- per-head QKV projection (fp32) ----------------
__global__ __launch_bounds__(256) void qkv_kernel(
    const float* __restrict__ xln,
    const float* __restrict__ Wq, const float* __restrict__ bq,
    const float* __restrict__ Wk, const float* __restrict__ bk,
    const float* __restrict__ Wv, const float* __restrict__ bv,
    float* __restrict__ qo, float* __restrict__ ko, float* __restrict__ vo) {
  const int bh = blockIdx.y;
  const int b = bh / H_, h = bh % H_;
  const int s0 = blockIdx.x * 64;
  const int tid = threadIdx.x;
  const int r = tid >> 2, eq = tid & 3, e0 = eq * 16;

  __shared__ float Wqs[64][64], Wks[64][64], Wvs[64][64];
  __shared__ float Xs[64][64];  // transposed: Xs[d][r]

  const float* wq = Wq + h * 4096;
  const float* wk = Wk + h * 4096;
  const float* wv = Wv + h * 4096;
#pragma unroll
  for (int i = 0; i < 16; ++i) {
    const int idx = tid + i * 256;
    (&Wqs[0][0])[idx] = wq[idx];
    (&Wks[0][0])[idx] = wk[idx];
    (&Wvs[0][0])[idx] = wv[idx];
    const int rr = idx >> 6, dd = idx & 63;
    Xs[dd][rr] = xln[(size_t)(b * S_ + s0 + rr) * D_ + h * 64 + dd];
  }
  __syncthreads();

  float4 aq[4] = {}, ak[4] = {}, av[4] = {};
#pragma unroll 8
  for (int d = 0; d < 64; ++d) {
    const float xv = Xs[d][r];
    const float4* wq4 = (const float4*)(&Wqs[d][e0]);
    const float4* wk4 = (const float4*)(&Wks[d][e0]);
    const float4* wv4 = (const float4*)(&Wvs[d][e0]);
#pragma unroll
    for (int j = 0; j < 4; ++j) {
      aq[j] = f4fma(aq[j], xv, wq4[j]);
      ak[j] = f4fma(ak[j], xv, wk4[j]);
      av[j] = f4fma(av[j], xv, wv4[j]);
    }
  }
  const size_t obase = ((size_t)bh * S_ + (s0 + r)) * 64 + e0;
#pragma unroll
  for (int j = 0; j < 4; ++j) {
    const float4 bq4 = *(const float4*)(bq + h * 64 + e0 + j * 4);
    const float4 bk4 = *(const float4*)(bk + h * 64 + e0 + j * 4);
    const float4 bv4 = *(const float4*)(bv + h * 64 + e0 + j * 4);
    float4 t;
    t = aq[j]; t.x += bq4.x; t.y += bq4.y; t.z += bq4.z; t.w += bq4.w;
    *(float4*)(qo + obase + j * 4) = t;
    t = ak[j]; t.x += bk4.x; t.y += bk4.y; t.z += bk4.z; t.w += bk4.w;
    *(float4*)(ko + obase + j * 4) = t;
    t = av[j]; t.x += bv4.x; t.y += bv4.y; t.z += bv4.z; t.w += bv4.w;
    *(float4*)(vo + obase + j * 4) = t;
  }
}

// ---------------- flash attention (fp32) + fused residual ----------------
__global__ __launch_bounds__(256) void attn_kernel(
    const float* __restrict__ q, const float* __restrict__ k,
    const float* __restrict__ v, const float* __restrict__ xin,
    float* __restrict__ o) {
  const int bh = blockIdx.y;
  const int b = bh / H_, h = bh % H_;
  const int q0 = blockIdx.x * 64;
  const int tid = threadIdx.x;
  const int tn = tid & 15, tm = tid >> 4;

  __shared__ float Qt[64][68];
  __shared__ float buf[64][68];
  __shared__ float Pt[64][68];
  __shared__ float m_s[64], l_s[64], a_s[64];

  const float* qp = q + ((size_t)bh * S_ + q0) * 64;
#pragma unroll
  for (int i = 0; i < 16; ++i) {
    const int idx = tid + i * 256;
    const int rr = idx >> 6, dd = idx & 63;
    Qt[dd][rr] = qp[idx] * 0.125f;
  }
  if (tid < 64) { m_s[tid] = -INFINITY; l_s[tid] = 0.0f; }
  float4 oa[4] = {};
  __syncthreads();

  const float* kp = k + (size_t)bh * S_ * 64;
  const float* vp = v + (size_t)bh * S_ * 64;

  for (int kt = 0; kt < 16; ++kt) {
    const float* kp2 = kp + kt * 4096;
#pragma unroll
    for (int i = 0; i < 16; ++i) {
      const int idx = tid + i * 256;
      const int tt = idx >> 6, dd = idx & 63;
      buf[dd][tt] = kp2[idx];
    }
    __syncthreads();

    float4 sc[4] = {};
#pragma unroll 8
    for (int d = 0; d < 64; ++d) {
      const float4 kf = *(const float4*)(&buf[d][tn * 4]);
      const float4 qf = *(const float4*)(&Qt[d][tm * 4]);
      const float qv[4] = {qf.x, qf.y, qf.z, qf.w};
#pragma unroll
      for (int i = 0; i < 4; ++i) sc[i] = f4fma(sc[i], qv[i], kf);
    }
#pragma unroll
    for (int i = 0; i < 4; ++i) {
      Pt[tn * 4 + 0][tm * 4 + i] = sc[i].x;
      Pt[tn * 4 + 1][tm * 4 + i] = sc[i].y;
      Pt[tn * 4 + 2][tm * 4 + i] = sc[i].z;
      Pt[tn * 4 + 3][tm * 4 + i] = sc[i].w;
    }
    __syncthreads();

    if (tid < 64) {
      const int qq = tid;
      const float mold = m_s[qq];
      float tmax = -INFINITY;
#pragma unroll 8
      for (int t = 0; t < 64; ++t) tmax = fmaxf(tmax, Pt[t][qq]);
      const float mnew = fmaxf(mold, tmax);
      const float corr = __expf(mold - mnew);
      float sum = 0.0f;
#pragma unroll 8
      for (int t = 0; t < 64; ++t) {
        const float pv = __expf(Pt[t][qq] - mnew);
        Pt[t][qq] = pv;
        sum += pv;
      }
      l_s[qq] = l_s[qq] * corr + sum;
      m_s[qq] = mnew;
      a_s[qq] = corr;
    } else {
      const float* vp2 = vp + kt * 4096;
      for (int i2 = tid - 64; i2 < 4096; i2 += 192) {
        const int tt = i2 >> 6, dd = i2 & 63;
        buf[tt][dd] = vp2[i2];
      }
    }
    __syncthreads();

#pragma unroll
    for (int i = 0; i < 4; ++i) {
      const float c = a_s[tm * 4 + i];
      oa[i].x *= c; oa[i].y *= c; oa[i].z *= c; oa[i].w *= c;
    }
#pragma unroll 8
    for (int t = 0; t < 64; ++t) {
      const float4 p4 = *(const float4*)(&Pt[t][tm * 4]);
      const float4 v4 = *(const float4*)(&buf[t][tn * 4]);
      const float pv[4] = {p4.x, p4.y, p4.z, p4.w};
#pragma unroll
      for (int i = 0; i < 4; ++i) oa[i] = f4fma(oa[i], pv[i], v4);
    }
    __syncthreads();
  }

  float* op = o + ((size_t)(b * S_) + q0) * D_ + h * 64 + tn * 4;
  const float* rp = xin + ((size_t)(b * S_) + q0) * D_ + h * 64 + tn * 4;
#pragma unroll
  for (int i = 0; i < 4; ++i) {
    const float invl = 1.0f / l_s[tm * 4 + i];
    const float4 rx = *(const float4*)(rp + (size_t)(tm * 4 + i) * D_);
    float4 t = oa[i];
    t.x = t.x * invl + rx.x; t.y = t.y * invl + rx.y;
    t.z = t.z * invl + rx.z; t.w = t.w * invl + rx.w;
    *(float4*)(op + (size_t)(tm * 4 + i) * D_) = t;
  }
}

// ---------------- bf16 MFMA GEMM, m97 structure ----------------
// C[M x N] = A[M x K] @ B[K x N], A bf16 row-major, Bt = B^T bf16 (N x K).
// 128x128 tile, 4 waves x (64x64), 16x16x32 MFMA, BK=32,
// global_load_lds width-16 staging. Optional exact-GELU / +resid epilogue.
template <int N, int K, bool GELU, bool RESID, bool OUT_BF16>
__global__ __launch_bounds__(256) void mfma_gemm(
    const ushort_t* __restrict__ A, const ushort_t* __restrict__ Bt,
    const float* __restrict__ resid, void* __restrict__ Cout) {
  const int mb = blockIdx.y * 128;
  const int nb = blockIdx.x * 128;
  const int tid = threadIdx.x;
  const int wave = tid >> 6, lane = tid & 63;
  const int wm = (wave >> 1) * 64, wn = (wave & 1) * 64;

  __shared__ ushort_t Asp[128 * 32];  // [m][k], k contiguous
  __shared__ ushort_t Bsp[128 * 32];  // [n][k], k contiguous

  const int srow = wave * 16 + (lane >> 2);  // staging row within 64-half
  const int skoff = (lane & 3) * 8;          // staging k offset (8 bf16 = 16B)

  floatx4 acc[4][4] = {};  // acc[mtile][ntile]

  for (int kb = 0; kb < K; kb += 32) {
#pragma unroll
    for (int j = 0; j < 2; ++j) {
      const int row = j * 64 + srow;
      __builtin_amdgcn_global_load_lds(
          (const __attribute__((address_space(1))) unsigned int*)
              (A + (size_t)(mb + row) * K + kb + skoff),
          (__attribute__((address_space(3))) unsigned int*)
              (Asp + (size_t)row * 32 + skoff),
          16, 0, 0);
      __builtin_amdgcn_global_load_lds(
          (const __attribute__((address_space(1))) unsigned int*)
              (Bt + (size_t)(nb + row) * K + kb + skoff),
          (__attribute__((address_space(3))) unsigned int*)
              (Bsp + (size_t)row * 32 + skoff),
          16, 0, 0);
    }
    __syncthreads();

    const short8* As8 = (const short8*)Asp;  // index = m*4 + k/8
    const short8* Bs8 = (const short8*)Bsp;
    const int lrow = lane & 15, lkq = lane >> 4;  // k = lkq*8
    short8 af[4], bfr[4];
#pragma unroll
    for (int i = 0; i < 4; ++i) {
      af[i]  = As8[(wm + i * 16 + lrow) * 4 + lkq];
      bfr[i] = Bs8[(wn + i * 16 + lrow) * 4 + lkq];
    }
#pragma unroll
    for (int i = 0; i < 4; ++i)
#pragma unroll
      for (int j = 0; j < 4; ++j)
        acc[i][j] = __builtin_amdgcn_mfma_f32_16x16x32_bf16(
            af[i], bfr[j], acc[i][j], 0, 0, 0);
    __syncthreads();
  }

  // epilogue: C/D layout col=lane&15, row=(lane>>4)*4+reg
  const int lcol = lane & 15, lr4 = (lane >> 4) * 4;
#pragma unroll
  for (int i = 0; i < 4; ++i) {
#pragma unroll
    for (int r = 0; r < 4; ++r) {
      const int m = mb + wm + i * 16 + lr4 + r;
#pragma unroll
      for (int j = 0; j < 4; ++j) {
        const int col = nb + wn + j * 16 + lcol;
        float vv = acc[i][j][r];
        if (GELU) vv = 0.5f * vv * (1.0f + erff(vv * 0.70710678f));
        if (RESID) vv += resid[(size_t)m * N + col];
        if (OUT_BF16)
          ((ushort_t*)Cout)[(size_t)m * N + col] = f2bf(vv);
        else
          ((float*)Cout)[(size_t)m * N + col] = vv;
      }
    }
  }
}

extern "C" void kernel_launch(void* const* d_in, const int* in_sizes, int n_in,
                              void* d_out, int out_size, void* d_ws, size_t ws_size,
                              hipStream_t stream) {
  (void)in_sizes; (void)n_in; (void)out_size; (void)ws_size;
  const float* x     = (const float*)d_in[0];
  const float* ln1_g = (const float*)d_in[1];
  const float* ln1_b = (const float*)d_in[2];
  const float* Wq    = (const float*)d_in[3];
  const float* bq    = (const float*)d_in[4];
  const float* Wk    = (const float*)d_in[5];
  const float* bk    = (const float*)d_in[6];
  const float* Wv    = (const float*)d_in[7];
  const float* bv    = (const float*)d_in[8];
  const float* ln2_g = (const float*)d_in[9];
  const float* ln2_b = (const float*)d_in[10];
  const float* W1    = (const float*)d_in[11];
  const float* W2    = (const float*)d_in[12];
  float* out = (float*)d_out;
  float* ws  = (float*)d_ws;

  const size_t n = (size_t)B_ * S_ * D_;  // 6,291,456
  float* xln  = ws;          // LN1 out (fp32)
  float* qb   = ws + n;
  float* kb   = ws + 2 * n;
  float* vb   = ws + 3 * n;
  float* out1 = ws + 4 * n;  // x + attn (fp32)
  ushort_t* ub  = (ushort_t*)(ws + 5 * n);
  ushort_t* xbf = ub;                       // LN2 out bf16 (8192 x 768)
  ushort_t* act = ub + n;                   // gelu acts bf16 (8192 x 3072)
  ushort_t* Wt1 = act + (size_t)8192 * 3072;        // 3072 x 768
  ushort_t* Wt2 = Wt1 + (size_t)3072 * 768;         // 768 x 3072
  // total ws ~= 198 MB

  transpose_cast<<<dim3(96, 24), dim3(256), 0, stream>>>(W1, Wt1, 768, 3072);
  transpose_cast<<<dim3(24, 96), dim3(256), 0, stream>>>(W2, Wt2, 3072, 768);
  ln_kernel<false><<<dim3(8192), dim3(256), 0, stream>>>(x, ln1_g, ln1_b, xln);
  qkv_kernel<<<dim3(16, 96), dim3(256), 0, stream>>>(xln, Wq, bq, Wk, bk, Wv, bv,
                                                     qb, kb, vb);
  attn_kernel<<<dim3(16, 96), dim3(256), 0, stream>>>(qb, kb, vb, x, out1);
  ln_kernel<true><<<dim3(8192), dim3(256), 0, stream>>>(out1, ln2_g, ln2_b, xbf);
  mfma_gemm<3072, 768, true, false, true>
      <<<dim3(24, 64), dim3(256), 0, stream>>>(xbf, Wt1, nullptr, act);
  mfma_gemm<768, 3072, false, true, false>
      <<<dim3(6, 64), dim3(256), 0, stream>>>(act, Wt2, out1, out);
}

// Round 3
// 477.028 us; speedup vs baseline: 3.6444x; 1.8798x over previous
//
#include <hip/hip_runtime.h>
#include <math.h>

#define B_ 8
#define S_ 1024
#define D_ 768
#define H_ 12
// DH = 64
#define QSCALE 0.18033688011112042f  // 0.125 * log2(e): softmax done base-2

typedef __attribute__((ext_vector_type(8))) short short8;
typedef __attribute__((ext_vector_type(4))) float floatx4;
typedef unsigned short ushort_t;

__device__ __forceinline__ ushort_t f2bf(float f) {  // RNE fp32 -> bf16
  unsigned int u = __builtin_bit_cast(unsigned int, f);
  u += 0x7fffu + ((u >> 16) & 1u);
  return (ushort_t)(u >> 16);
}

// ---------------- LayerNorm (one block per row of 768), bf16 out ----------
__global__ __launch_bounds__(256) void ln_bf16(
    const float* __restrict__ in, const float* __restrict__ g,
    const float* __restrict__ bias, ushort_t* __restrict__ out) {
  const int row = blockIdx.x;
  const int tid = threadIdx.x;
  const float* p = in + (size_t)row * D_;
  const float v0 = p[tid], v1 = p[tid + 256], v2 = p[tid + 512];
  __shared__ float red[256];
  red[tid] = v0 + v1 + v2;
  __syncthreads();
  for (int off = 128; off > 0; off >>= 1) {
    if (tid < off) red[tid] += red[tid + off];
    __syncthreads();
  }
  const float mean = red[0] * (1.0f / D_);
  __syncthreads();
  const float d0 = v0 - mean, d1 = v1 - mean, d2 = v2 - mean;
  red[tid] = d0 * d0 + d1 * d1 + d2 * d2;
  __syncthreads();
  for (int off = 128; off > 0; off >>= 1) {
    if (tid < off) red[tid] += red[tid + off];
    __syncthreads();
  }
  const float rstd = rsqrtf(red[0] * (1.0f / D_) + 1e-5f);
  ushort_t* q = out + (size_t)row * D_;
  q[tid]       = f2bf(d0 * rstd * g[tid]       + bias[tid]);
  q[tid + 256] = f2bf(d1 * rstd * g[tid + 256] + bias[tid + 256]);
  q[tid + 512] = f2bf(d2 * rstd * g[tid + 512] + bias[tid + 512]);
}

// ---------------- transpose + cast: W (K x N fp32) -> Wt (N x K bf16) -----
__global__ __launch_bounds__(256) void transpose_cast(
    const float* __restrict__ W, ushort_t* __restrict__ Wt, int Kdim, int Ndim) {
  __shared__ float tile[32][33];
  const int n0 = blockIdx.x * 32, k0 = blockIdx.y * 32;
  const int tx = threadIdx.x & 31, ty = threadIdx.x >> 5;  // ty 0..7
#pragma unroll
  for (int i = 0; i < 32; i += 8)
    tile[ty + i][tx] = W[(size_t)(k0 + ty + i) * Ndim + n0 + tx];
  __syncthreads();
#pragma unroll
  for (int i = 0; i < 32; i += 8)
    Wt[(size_t)(n0 + ty + i) * Kdim + k0 + tx] = f2bf(tile[tx][ty + i]);
}

// -------- per-head 64x64 weight transpose+cast (Wq/Wk/Wv -> e-major bf16) --
__global__ __launch_bounds__(256) void trans_w64(
    const float* __restrict__ Wq, const float* __restrict__ Wk,
    const float* __restrict__ Wv, ushort_t* __restrict__ Wqt,
    ushort_t* __restrict__ Wkt, ushort_t* __restrict__ Wvt) {
  const int h = blockIdx.x;
  const float* W = blockIdx.y == 0 ? Wq : blockIdx.y == 1 ? Wk : Wv;
  ushort_t* O = blockIdx.y == 0 ? Wqt : blockIdx.y == 1 ? Wkt : Wvt;
  __shared__ float t[64][65];
  const int tid = threadIdx.x;
#pragma unroll
  for (int i = 0; i < 16; ++i) {
    const int idx = tid + i * 256;
    t[idx >> 6][idx & 63] = W[h * 4096 + idx];
  }
  __syncthreads();
#pragma unroll
  for (int i = 0; i < 16; ++i) {
    const int idx = tid + i * 256;
    O[h * 4096 + idx] = f2bf(t[idx & 63][idx >> 6]);  // O[e][d] = W[d][e]
  }
}

// ---------------- QKV projection, bf16 MFMA, no LDS, no barriers ----------
// grid (64, 12): block = 128 rows x head h. Per wave: 2 m-tiles of 16 rows.
// Q output pre-scaled by QSCALE (softmax base-2 + 1/sqrt(DH)).
__global__ __launch_bounds__(256) void qkv_mfma(
    const ushort_t* __restrict__ xbf,
    const ushort_t* __restrict__ Wqt, const ushort_t* __restrict__ Wkt,
    const ushort_t* __restrict__ Wvt,
    const float* __restrict__ bq, const float* __restrict__ bk,
    const float* __restrict__ bv,
    ushort_t* __restrict__ qo, ushort_t* __restrict__ ko,
    ushort_t* __restrict__ vo) {
  const int h = blockIdx.y;
  const int mb = blockIdx.x * 128;
  const int tid = threadIdx.x;
  const int wave = tid >> 6, lane = tid & 63;
  const int lc = lane & 15, kq = lane >> 4;
  const int wm = wave * 32;

  short8 af[2][2];  // A-frags: [m-tile][k-chunk]
#pragma unroll
  for (int mi = 0; mi < 2; ++mi)
#pragma unroll
    for (int kc = 0; kc < 2; ++kc)
      af[mi][kc] = *(const short8*)(xbf + (size_t)(mb + wm + mi * 16 + lc) * D_ +
                                    h * 64 + kc * 32 + kq * 8);

  const ushort_t* Wp[3] = {Wqt + h * 4096, Wkt + h * 4096, Wvt + h * 4096};
  floatx4 acc[3][2][4] = {};
#pragma unroll
  for (int w3 = 0; w3 < 3; ++w3)
#pragma unroll
    for (int n = 0; n < 4; ++n)
#pragma unroll
      for (int kc = 0; kc < 2; ++kc) {
        const short8 bfv =
            *(const short8*)(Wp[w3] + (n * 16 + lc) * 64 + kc * 32 + kq * 8);
#pragma unroll
        for (int mi = 0; mi < 2; ++mi)
          acc[w3][mi][n] = __builtin_amdgcn_mfma_f32_16x16x32_bf16(
              af[mi][kc], bfv, acc[w3][mi][n], 0, 0, 0);
      }

  const int b = mb >> 10;
  const size_t obase = (size_t)(b * H_ + h) * (S_ * 64);
  const float* bias[3] = {bq + h * 64, bk + h * 64, bv + h * 64};
  ushort_t* outp[3] = {qo, ko, vo};
#pragma unroll
  for (int w3 = 0; w3 < 3; ++w3)
#pragma unroll
    for (int n = 0; n < 4; ++n) {
      const int e = n * 16 + lc;
      const float bvv = bias[w3][e];
#pragma unroll
      for (int mi = 0; mi < 2; ++mi)
#pragma unroll
        for (int r = 0; r < 4; ++r) {
          const int sl = (mb & 1023) + wm + mi * 16 + kq * 4 + r;
          float v = acc[w3][mi][n][r] + bvv;
          if (w3 == 0) v *= QSCALE;
          outp[w3][obase + (size_t)sl * 64 + e] = f2bf(v);
        }
    }
}

// ---------------- V transpose: [bh][s][d] -> Vt [bh][d][s] ----------------
__global__ __launch_bounds__(256) void vtrans(
    const ushort_t* __restrict__ V, ushort_t* __restrict__ Vt) {
  const int bh = blockIdx.y;
  const int s0 = blockIdx.x * 128;
  const int tid = threadIdx.x;
  __shared__ ushort_t t[64][136];
#pragma unroll
  for (int i = 0; i < 4; ++i) {
    const int idx = tid + i * 256;  // 0..1023
    const int s = idx >> 3, dc = (idx & 7) * 8;
    const short8 v8 = *(const short8*)(V + (size_t)(bh * S_ + s0 + s) * 64 + dc);
#pragma unroll
    for (int j = 0; j < 8; ++j) t[dc + j][s] = (ushort_t)v8[j];
  }
  __syncthreads();
#pragma unroll
  for (int i = 0; i < 4; ++i) {
    const int idx = tid + i * 256;
    const int d = idx >> 4, sc = (idx & 15) * 8;
    const short8 v8 = *(const short8*)(&t[d][sc]);
    *(short8*)(Vt + (size_t)(bh * 64 + d) * S_ + s0 + sc) = v8;
  }
}

// ---------------- flash attention, bf16 MFMA, barrier-free ----------------
// grid (16, 96): block = 64 queries x (b,h). Wave w owns queries w*16..+15.
// QK B-frags straight from K[key][d]; PV B-frags from Vt[d][s]; P round-trips
// through per-wave LDS. Online softmax in base-2 (Q pre-scaled). Fused +x.
__global__ __launch_bounds__(256) void attn_mfma(
    const ushort_t* __restrict__ qb, const ushort_t* __restrict__ kb,
    const ushort_t* __restrict__ vt, const float* __restrict__ x,
    float* __restrict__ out1) {
  const int bh = blockIdx.y;
  const int q0 = blockIdx.x * 64;
  const int tid = threadIdx.x;
  const int wave = tid >> 6, lane = tid & 63;
  const int lc = lane & 15, kq = lane >> 4;

  __shared__ ushort_t Pw[4][16][72];  // per-wave P buffer (pad 72: 16B-aligned rows)

  const ushort_t* qp = qb + (size_t)bh * (S_ * 64);
  const ushort_t* kp = kb + (size_t)bh * (S_ * 64);
  const ushort_t* vp = vt + (size_t)bh * (S_ * 64);

  short8 qf[2];
#pragma unroll
  for (int kc = 0; kc < 2; ++kc)
    qf[kc] = *(const short8*)(qp + (size_t)(q0 + wave * 16 + lc) * 64 +
                              kc * 32 + kq * 8);

  float m_r[4], l_r[4];
#pragma unroll
  for (int r = 0; r < 4; ++r) { m_r[r] = -INFINITY; l_r[r] = 0.0f; }
  floatx4 oacc[4] = {};

  for (int kt = 0; kt < 16; ++kt) {
    // K B-frags (natural layout == B-operand layout)
    const ushort_t* kpt = kp + kt * 4096;
    short8 kfr[4][2];
#pragma unroll
    for (int n = 0; n < 4; ++n)
#pragma unroll
      for (int kc = 0; kc < 2; ++kc)
        kfr[n][kc] =
            *(const short8*)(kpt + (size_t)(n * 16 + lc) * 64 + kc * 32 + kq * 8);
    floatx4 sacc[4] = {};
#pragma unroll
    for (int n = 0; n < 4; ++n)
#pragma unroll
      for (int kc = 0; kc < 2; ++kc)
        sacc[n] = __builtin_amdgcn_mfma_f32_16x16x32_bf16(qf[kc], kfr[n][kc],
                                                          sacc[n], 0, 0, 0);
    // prefetch V B-frags (independent of softmax)
    short8 vfr[4][2];
#pragma unroll
    for (int n = 0; n < 4; ++n)
#pragma unroll
      for (int kc = 0; kc < 2; ++kc)
        vfr[n][kc] = *(const short8*)(vp + (size_t)(n * 16 + lc) * S_ + kt * 64 +
                                      kc * 32 + kq * 8);

    // ---- online softmax (wave-local; rows r over lane groups of 16) ----
    float mt[4];
#pragma unroll
    for (int r = 0; r < 4; ++r)
      mt[r] = fmaxf(fmaxf(sacc[0][r], sacc[1][r]), fmaxf(sacc[2][r], sacc[3][r]));
#pragma unroll
    for (int msk = 1; msk < 16; msk <<= 1)
#pragma unroll
      for (int r = 0; r < 4; ++r)
        mt[r] = fmaxf(mt[r], __shfl_xor(mt[r], msk, 64));
    float al[4];
#pragma unroll
    for (int r = 0; r < 4; ++r) {
      const float mn = fmaxf(m_r[r], mt[r]);
      al[r] = exp2f(m_r[r] - mn);  // first tile: exp2(-inf) = 0
      m_r[r] = mn;
    }
    float pr[4][4];
#pragma unroll
    for (int n = 0; n < 4; ++n)
#pragma unroll
      for (int r = 0; r < 4; ++r) pr[n][r] = exp2f(sacc[n][r] - m_r[r]);
    float sm[4];
#pragma unroll
    for (int r = 0; r < 4; ++r)
      sm[r] = (pr[0][r] + pr[1][r]) + (pr[2][r] + pr[3][r]);
#pragma unroll
    for (int msk = 1; msk < 16; msk <<= 1)
#pragma unroll
      for (int r = 0; r < 4; ++r) sm[r] += __shfl_xor(sm[r], msk, 64);
#pragma unroll
    for (int r = 0; r < 4; ++r) l_r[r] = l_r[r] * al[r] + sm[r];
#pragma unroll
    for (int n = 0; n < 4; ++n)
#pragma unroll
      for (int r = 0; r < 4; ++r) oacc[n][r] *= al[r];

    // ---- P: C-layout regs -> LDS [q][key] (bf16) -> A-frags ----
#pragma unroll
    for (int n = 0; n < 4; ++n)
#pragma unroll
      for (int r = 0; r < 4; ++r)
        Pw[wave][kq * 4 + r][n * 16 + lc] = f2bf(pr[n][r]);
    asm volatile("s_waitcnt lgkmcnt(0)" ::: "memory");
    short8 pf[2];
#pragma unroll
    for (int kc = 0; kc < 2; ++kc)
      pf[kc] = *(const short8*)(&Pw[wave][lc][kc * 32 + kq * 8]);
#pragma unroll
    for (int n = 0; n < 4; ++n)
#pragma unroll
      for (int kc = 0; kc < 2; ++kc)
        oacc[n] = __builtin_amdgcn_mfma_f32_16x16x32_bf16(pf[kc], vfr[n][kc],
                                                          oacc[n], 0, 0, 0);
  }

  const int b = bh / H_, h = bh % H_;
#pragma unroll
  for (int r = 0; r < 4; ++r) {
    const float inv = 1.0f / l_r[r];
    const int s_abs = q0 + wave * 16 + kq * 4 + r;
    const size_t base = (size_t)(b * S_ + s_abs) * D_ + h * 64;
#pragma unroll
    for (int n = 0; n < 4; ++n) {
      const int d = n * 16 + lc;
      out1[base + d] = oacc[n][r] * inv + x[base + d];
    }
  }
}

// ---------------- bf16 MFMA GEMM, m97 structure (FFN) ----------------
template <int N, int K, bool GELU, bool RESID, bool OUT_BF16>
__global__ __launch_bounds__(256) void mfma_gemm(
    const ushort_t* __restrict__ A, const ushort_t* __restrict__ Bt,
    const float* __restrict__ resid, void* __restrict__ Cout) {
  const int mb = blockIdx.y * 128;
  const int nb = blockIdx.x * 128;
  const int tid = threadIdx.x;
  const int wave = tid >> 6, lane = tid & 63;
  const int wm = (wave >> 1) * 64, wn = (wave & 1) * 64;

  __shared__ ushort_t Asp[128 * 32];
  __shared__ ushort_t Bsp[128 * 32];

  const int srow = wave * 16 + (lane >> 2);
  const int skoff = (lane & 3) * 8;

  floatx4 acc[4][4] = {};

  for (int kb = 0; kb < K; kb += 32) {
#pragma unroll
    for (int j = 0; j < 2; ++j) {
      const int row = j * 64 + srow;
      __builtin_amdgcn_global_load_lds(
          (const __attribute__((address_space(1))) unsigned int*)
              (A + (size_t)(mb + row) * K + kb + skoff),
          (__attribute__((address_space(3))) unsigned int*)
              (Asp + (size_t)row * 32 + skoff),
          16, 0, 0);
      __builtin_amdgcn_global_load_lds(
          (const __attribute__((address_space(1))) unsigned int*)
              (Bt + (size_t)(nb + row) * K + kb + skoff),
          (__attribute__((address_space(3))) unsigned int*)
              (Bsp + (size_t)row * 32 + skoff),
          16, 0, 0);
    }
    __syncthreads();

    const short8* As8 = (const short8*)Asp;
    const short8* Bs8 = (const short8*)Bsp;
    const int lrow = lane & 15, lkq = lane >> 4;
    short8 af[4], bfr[4];
#pragma unroll
    for (int i = 0; i < 4; ++i) {
      af[i]  = As8[(wm + i * 16 + lrow) * 4 + lkq];
      bfr[i] = Bs8[(wn + i * 16 + lrow) * 4 + lkq];
    }
#pragma unroll
    for (int i = 0; i < 4; ++i)
#pragma unroll
      for (int j = 0; j < 4; ++j)
        acc[i][j] = __builtin_amdgcn_mfma_f32_16x16x32_bf16(
            af[i], bfr[j], acc[i][j], 0, 0, 0);
    __syncthreads();
  }

  const int lcol = lane & 15, lr4 = (lane >> 4) * 4;
#pragma unroll
  for (int i = 0; i < 4; ++i)
#pragma unroll
    for (int r = 0; r < 4; ++r) {
      const int m = mb + wm + i * 16 + lr4 + r;
#pragma unroll
      for (int j = 0; j < 4; ++j) {
        const int col = nb + wn + j * 16 + lcol;
        float vv = acc[i][j][r];
        if (GELU) vv = 0.5f * vv * (1.0f + erff(vv * 0.70710678f));
        if (RESID) vv += resid[(size_t)m * N + col];
        if (OUT_BF16)
          ((ushort_t*)Cout)[(size_t)m * N + col] = f2bf(vv);
        else
          ((float*)Cout)[(size_t)m * N + col] = vv;
      }
    }
}

extern "C" void kernel_launch(void* const* d_in, const int* in_sizes, int n_in,
                              void* d_out, int out_size, void* d_ws, size_t ws_size,
                              hipStream_t stream) {
  (void)in_sizes; (void)n_in; (void)out_size; (void)ws_size;
  const float* x     = (const float*)d_in[0];
  const float* ln1_g = (const float*)d_in[1];
  const float* ln1_b = (const float*)d_in[2];
  const float* Wq    = (const float*)d_in[3];
  const float* bq    = (const float*)d_in[4];
  const float* Wk    = (const float*)d_in[5];
  const float* bk    = (const float*)d_in[6];
  const float* Wv    = (const float*)d_in[7];
  const float* bv    = (const float*)d_in[8];
  const float* ln2_g = (const float*)d_in[9];
  const float* ln2_b = (const float*)d_in[10];
  const float* W1    = (const float*)d_in[11];
  const float* W2    = (const float*)d_in[12];
  float* out = (float*)d_out;

  const size_t n = (size_t)B_ * S_ * D_;  // 6,291,456
  ushort_t* u = (ushort_t*)d_ws;
  ushort_t* xbf  = u;                 // LN1 out bf16
  ushort_t* qb   = xbf + n;           // [96][1024][64]
  ushort_t* kb   = qb + n;
  ushort_t* vb   = kb + n;
  ushort_t* vt   = vb + n;            // [96][64][1024]
  ushort_t* xbf2 = vt + n;            // LN2 out bf16
  ushort_t* act  = xbf2 + n;          // 8192 x 3072
  ushort_t* Wt1  = act + (size_t)8192 * 3072;
  ushort_t* Wt2  = Wt1 + (size_t)3072 * 768;
  ushort_t* Wqt  = Wt2 + (size_t)768 * 3072;
  ushort_t* Wkt  = Wqt + H_ * 4096;
  ushort_t* Wvt  = Wkt + H_ * 4096;
  float* out1 = (float*)(Wvt + H_ * 4096);  // x + attn (fp32), n floats
  // total ws ~= 161 MB

  trans_w64<<<dim3(12, 3), dim3(256), 0, stream>>>(Wq, Wk, Wv, Wqt, Wkt, Wvt);
  transpose_cast<<<dim3(96, 24), dim3(256), 0, stream>>>(W1, Wt1, 768, 3072);
  transpose_cast<<<dim3(24, 96), dim3(256), 0, stream>>>(W2, Wt2, 3072, 768);
  ln_bf16<<<dim3(8192), dim3(256), 0, stream>>>(x, ln1_g, ln1_b, xbf);
  qkv_mfma<<<dim3(64, 12), dim3(256), 0, stream>>>(xbf, Wqt, Wkt, Wvt,
                                                   bq, bk, bv, qb, kb, vb);
  vtrans<<<dim3(8, 96), dim3(256), 0, stream>>>(vb, vt);
  attn_mfma<<<dim3(16, 96), dim3(256), 0, stream>>>(qb, kb, vt, x, out1);
  ln_bf16<<<dim3(8192), dim3(256), 0, stream>>>(out1, ln2_g, ln2_b, xbf2);
  mfma_gemm<3072, 768, true, false, true>
      <<<dim3(24, 64), dim3(256), 0, stream>>>(xbf2, Wt1, nullptr, act);
  mfma_gemm<768, 3072, false, true, false>
      <<<dim3(6, 64), dim3(256), 0, stream>>>(act, Wt2, out1, out);
}